// Round 7
// baseline (270.346 us; speedup 1.0000x reference)
//
#include <hip/hip_runtime.h>
#include <hip/hip_bf16.h>

typedef unsigned short u16;
typedef float  f32x16 __attribute__((ext_vector_type(16)));
typedef short  bf16x8 __attribute__((ext_vector_type(8)));
typedef u16    u16x8  __attribute__((ext_vector_type(8)));

#define CDIM 1024
#define HW   16384

typedef const void __attribute__((address_space(1))) gvoid;
typedef void __attribute__((address_space(3))) svoid;

__device__ __forceinline__ u16 f2bf(float f) {
    unsigned u = __float_as_uint(f);
    u += 0x7fffu + ((u >> 16) & 1u);            // RNE
    return (u16)(u >> 16);
}
__device__ __forceinline__ float bf2f(u16 h) { return __uint_as_float(((unsigned)h) << 16); }

__device__ __forceinline__ f32x16 mfma32(bf16x8 a, bf16x8 b, f32x16 c) {
    return __builtin_amdgcn_mfma_f32_32x32x16_bf16(a, b, c, 0, 0, 0);
}

// ---------------- K1: x(f32) -> hi, lo (split bf16) + hiT (fused transpose) ----------------
__global__ __launch_bounds__(256) void k_convert(const float* __restrict__ x,
                                                 u16* __restrict__ hi, u16* __restrict__ lo,
                                                 u16* __restrict__ hiT)
{
    __shared__ u16 tile[64][72];
    const int pb = blockIdx.x;   // HW tile (0..255)
    const int cb = blockIdx.y;   // C tile  (0..15)
    const int tid = threadIdx.x;
#pragma unroll
    for (int pass = 0; pass < 4; ++pass) {
        const int i  = (tid >> 4) + (pass << 4);    // c-row in tile 0..63
        const int j4 = (tid & 15) << 2;             // p-col in tile
        const long gidx = (long)(cb * 64 + i) * HW + pb * 64 + j4;
        const float4 v = *(const float4*)(x + gidx);
        ushort4 h, l;
        h.x = f2bf(v.x); l.x = f2bf(v.x - bf2f(h.x));
        h.y = f2bf(v.y); l.y = f2bf(v.y - bf2f(h.y));
        h.z = f2bf(v.z); l.z = f2bf(v.z - bf2f(h.z));
        h.w = f2bf(v.w); l.w = f2bf(v.w - bf2f(h.w));
        *(ushort4*)(hi + gidx) = h;
        *(ushort4*)(lo + gidx) = l;
        tile[i][j4 + 0] = h.x; tile[i][j4 + 1] = h.y;
        tile[i][j4 + 2] = h.z; tile[i][j4 + 3] = h.w;
    }
    __syncthreads();
#pragma unroll
    for (int pass = 0; pass < 2; ++pass) {
        const int j  = (tid >> 3) + (pass << 5);    // p-row 0..63
        const int c8 = (tid & 7) << 3;
        u16x8 v;
#pragma unroll
        for (int q = 0; q < 8; ++q) v[q] = tile[c8 + q][j];
        *(u16x8*)(hiT + (long)(pb * 64 + j) * CDIM + cb * 64 + c8) = v;
    }
}

// ---- LDS involution placement (R4-R6-proven staging/read pair), 256-thread version ----
// Granule (row, s) of a 128x64 bf16 tile lives at u16 offset (row>>3)*512 + s*64 + ((row&7)^s)*8.
// Staged linearly by global_load_lds (wave-uniform base + lane*16B) with the inverse
// permutation on the global source address; reads apply the same involution.
__device__ __forceinline__ void stage_tile(const u16* __restrict__ gbase, long ldg,
                                           int ktile, u16* seg, int tid)
{
    const int lane = tid & 63;
    const int wv   = tid >> 6;                  // 0..3
    const int s    = lane >> 3;                 // k-slot 0..7 (16B granules)
    const int r7   = (lane & 7) ^ s;            // row within 8-row region
    const int col  = s << 3;                    // element col of the granule
#pragma unroll
    for (int q = 0; q < 4; ++q) {
        const int j = wv + (q << 2);            // region 0..15 (8 rows each)
        const u16* src = gbase + (long)((j << 3) + r7) * ldg + (ktile << 6) + col;
        __builtin_amdgcn_global_load_lds((gvoid*)src, (svoid*)(seg + (j << 9)), 16, 0, 0);
    }
}

__device__ __forceinline__ bf16x8 rd_frag(const u16* seg, int row, int s)
{
    const int off = ((row >> 3) << 9) + (s << 6) + (((row & 7) ^ s) << 3);
    return *(const bf16x8*)(seg + off);
}

// ---------------- K2: E1p = H*H^T, E2p = H*L^T (split-K partials) ----------------
// R1-champion body (128x128 tile, 4 waves 2x2, 6-read:8-MFMA per kk, 3-tile staging with
// shared A).  NEW vs R1: 3-deep LDS pipeline + raw s_barrier + counted vmcnt(12) — the
// __syncthreads() in R1 compiled to "s_waitcnt vmcnt(0)" which drained the prefetch every
// K-step (the documented ~20% barrier-drain stall).  Now tile t+2 stays in flight across
// the barrier; we wait only for t+1 (issued ~2 K-steps earlier).
__global__ __launch_bounds__(256) void k_energy(const u16* __restrict__ hi, const u16* __restrict__ lo,
                                                float* __restrict__ E1p, float* __restrict__ E2p,
                                                int kchunk)
{
    __shared__ u16 sA [3][8192];   // 3 x 16 KB
    __shared__ u16 sBh[3][8192];
    __shared__ u16 sBl[3][8192];   // total 144 KB -> 1 block/CU

    const int tid  = threadIdx.x;
    const int lane = tid & 63;
    const int w    = tid >> 6;
    const int wm   = w >> 1;          // 0..1
    const int wn   = w & 1;           // 0..1
    const int l31  = lane & 31;
    const int lh   = lane >> 5;       // k-half

    const int bj = blockIdx.x, bi = blockIdx.y, ks = blockIdx.z;
    const long k0 = (long)ks * kchunk;
    const int nkt = kchunk >> 6;

    const u16* Ab = hi + (long)bi * 128 * HW + k0;
    const u16* Bh = hi + (long)bj * 128 * HW + k0;
    const u16* Bl = lo + (long)bj * 128 * HW + k0;

    f32x16 acc1[2][2], acc2[2][2];
    {
        f32x16 z;
#pragma unroll
        for (int r = 0; r < 16; ++r) z[r] = 0.f;
#pragma unroll
        for (int m = 0; m < 2; ++m)
#pragma unroll
            for (int n = 0; n < 2; ++n) { acc1[m][n] = z; acc2[m][n] = z; }
    }

    // rotating buffer pointers: c* = compute (t), n* = next (t+1), f* = future (t+2 target)
    u16 *cA = sA[0],  *nA = sA[1],  *fA = sA[2];
    u16 *cBh = sBh[0], *nBh = sBh[1], *fBh = sBh[2];
    u16 *cBl = sBl[0], *nBl = sBl[1], *fBl = sBl[2];

    // prologue: stage tiles 0 and 1 (24 loads/wave outstanding), wait tile 0 (12 newest fly on)
    stage_tile(Ab, HW, 0, cA,  tid);
    stage_tile(Bh, HW, 0, cBh, tid);
    stage_tile(Bl, HW, 0, cBl, tid);
    stage_tile(Ab, HW, 1, nA,  tid);
    stage_tile(Bh, HW, 1, nBh, tid);
    stage_tile(Bl, HW, 1, nBl, tid);
    asm volatile("s_waitcnt vmcnt(12)" ::: "memory");
    __builtin_amdgcn_sched_barrier(0);
    __builtin_amdgcn_s_barrier();
    __builtin_amdgcn_sched_barrier(0);

    for (int t = 0; t < nkt; ++t) {
        const bool more = (t + 2 < nkt);
        if (more) {
            stage_tile(Ab, HW, t + 2, fA,  tid);
            stage_tile(Bh, HW, t + 2, fBh, tid);
            stage_tile(Bl, HW, t + 2, fBl, tid);
        }

        // ---- R1-exact compute body on tile t ----
#pragma unroll
        for (int kk = 0; kk < 4; ++kk) {
            const int s = (kk << 1) + lh;
            bf16x8 a0 = rd_frag(cA,  wm * 64 + l31,      s);
            bf16x8 a1 = rd_frag(cA,  wm * 64 + 32 + l31, s);
            bf16x8 b0 = rd_frag(cBh, wn * 64 + l31,      s);
            bf16x8 b1 = rd_frag(cBh, wn * 64 + 32 + l31, s);
            bf16x8 c0 = rd_frag(cBl, wn * 64 + l31,      s);
            bf16x8 c1 = rd_frag(cBl, wn * 64 + 32 + l31, s);
            acc1[0][0] = mfma32(a0, b0, acc1[0][0]);
            acc1[0][1] = mfma32(a0, b1, acc1[0][1]);
            acc1[1][0] = mfma32(a1, b0, acc1[1][0]);
            acc1[1][1] = mfma32(a1, b1, acc1[1][1]);
            acc2[0][0] = mfma32(a0, c0, acc2[0][0]);
            acc2[0][1] = mfma32(a0, c1, acc2[0][1]);
            acc2[1][0] = mfma32(a1, c0, acc2[1][0]);
            acc2[1][1] = mfma32(a1, c1, acc2[1][1]);
        }

        // wait for tile t+1 only; tile t+2's 12 loads stay in flight across the barrier
        if (more) asm volatile("s_waitcnt vmcnt(12)" ::: "memory");
        else      asm volatile("s_waitcnt vmcnt(0)"  ::: "memory");
        __builtin_amdgcn_sched_barrier(0);
        __builtin_amdgcn_s_barrier();
        __builtin_amdgcn_sched_barrier(0);

        // rotate buffers
        u16* tA = cA;  cA = nA;  nA = fA;  fA = tA;
        u16* tBh = cBh; cBh = nBh; nBh = fBh; fBh = tBh;
        u16* tBl = cBl; cBl = nBl; nBl = fBl; fBl = tBl;
    }

    // 32x32 C/D layout (R1/R2-verified): col = lane&31, row = (r&3) + 8*(r>>2) + 4*(lane>>5)
    float* e1 = E1p + (long)ks * (CDIM * CDIM);
    float* e2 = E2p + (long)ks * (CDIM * CDIM);
#pragma unroll
    for (int m = 0; m < 2; ++m)
#pragma unroll
        for (int n = 0; n < 2; ++n)
#pragma unroll
            for (int r = 0; r < 16; ++r) {
                const int row = bi * 128 + wm * 64 + m * 32 + (r & 3) + ((r >> 2) << 3) + (lh << 2);
                const int col = bj * 128 + wn * 64 + n * 32 + l31;
                const long idx = (long)row * CDIM + col;
                e1[idx] = acc1[m][n][r];
                e2[idx] = acc2[m][n][r];
            }
}

// ---------------- K2b: Esym = sum_ks (E1p + E2p + E2p^T), nsplit = 4 ----------------
__global__ __launch_bounds__(256) void k_symmetrize(const float* __restrict__ E1p,
                                                    const float* __restrict__ E2p,
                                                    float* __restrict__ Esym)
{
    __shared__ float tr[64][65];
    const int jb = blockIdx.x, ib = blockIdx.y, tid = threadIdx.x;
    float4 accv[4];
#pragma unroll
    for (int e4 = 0; e4 < 4; ++e4) {
        const int e = tid + (e4 << 8);
        const int i = e >> 4, j4 = (e & 15) << 2;
        float ax = 0, ay = 0, az = 0, aw = 0, bx = 0, by = 0, bz = 0, bw = 0;
#pragma unroll
        for (int ks = 0; ks < 4; ++ks) {
            const long base = (long)ks * (CDIM * CDIM);
            float4 p1 = *(const float4*)(E1p + base + (long)(ib * 64 + i) * CDIM + jb * 64 + j4);
            float4 p2 = *(const float4*)(E2p + base + (long)(ib * 64 + i) * CDIM + jb * 64 + j4);
            float4 p3 = *(const float4*)(E2p + base + (long)(jb * 64 + i) * CDIM + ib * 64 + j4);
            ax += p1.x + p2.x; ay += p1.y + p2.y; az += p1.z + p2.z; aw += p1.w + p2.w;
            bx += p3.x; by += p3.y; bz += p3.z; bw += p3.w;
        }
        accv[e4] = make_float4(ax, ay, az, aw);
        tr[i][j4 + 0] = bx; tr[i][j4 + 1] = by; tr[i][j4 + 2] = bz; tr[i][j4 + 3] = bw;
    }
    __syncthreads();
#pragma unroll
    for (int e4 = 0; e4 < 4; ++e4) {
        const int e = tid + (e4 << 8);
        const int i = e >> 4, j4 = (e & 15) << 2;
        float4 o = accv[e4];
        o.x += tr[j4 + 0][i]; o.y += tr[j4 + 1][i]; o.z += tr[j4 + 2][i]; o.w += tr[j4 + 3][i];
        *(float4*)(Esym + (long)(ib * 64 + i) * CDIM + jb * 64 + j4) = o;
    }
}

// ---------------- K3: att = softmax(-E) rows, stored bf16 ----------------
__global__ __launch_bounds__(256) void k_softmax(const float* __restrict__ E, u16* __restrict__ att)
{
    __shared__ float red[4];
    __shared__ float bcast;
    const int row = blockIdx.x, tid = threadIdx.x;
    const float4 v = ((const float4*)(E + (long)row * CDIM))[tid];

    float m = fminf(fminf(v.x, v.y), fminf(v.z, v.w));
#pragma unroll
    for (int s = 32; s > 0; s >>= 1) m = fminf(m, __shfl_down(m, s));
    if ((tid & 63) == 0) red[tid >> 6] = m;
    __syncthreads();
    if (tid == 0) bcast = fminf(fminf(red[0], red[1]), fminf(red[2], red[3]));
    __syncthreads();
    m = bcast;  // row min of E == row max of -E

    const float px = expf(m - v.x), py = expf(m - v.y), pz = expf(m - v.z), pw = expf(m - v.w);
    float s4 = px + py + pz + pw;
#pragma unroll
    for (int s = 32; s > 0; s >>= 1) s4 += __shfl_down(s4, s);
    if ((tid & 63) == 0) red[tid >> 6] = s4;
    __syncthreads();
    if (tid == 0) bcast = red[0] + red[1] + red[2] + red[3];
    __syncthreads();
    const float inv = 1.0f / bcast;

    ushort4 o;
    o.x = f2bf(px * inv); o.y = f2bf(py * inv); o.z = f2bf(pz * inv); o.w = f2bf(pw * inv);
    ((ushort4*)(att + (long)row * CDIM))[tid] = o;
}

// ---------------- K4: out = gamma * (att @ q) + x ----------------
// R1-exact structure: 256 threads, 4 waves 2x2 (64x64 out each), 64 KB LDS -> 2 blocks/CU,
// double-buffered with stage-early.  (Proven fast inside R1's 179.5 total.)
__global__ __launch_bounds__(256) void k_out(const u16* __restrict__ att, const u16* __restrict__ qT,
                                             const float* __restrict__ x, const float* __restrict__ gamma,
                                             float* __restrict__ out)
{
    __shared__ u16 sA[2][8192];
    __shared__ u16 sB[2][8192];

    const int tid  = threadIdx.x;
    const int lane = tid & 63;
    const int w    = tid >> 6;
    const int wm   = w >> 1;          // 0..1
    const int wn   = w & 1;           // 0..1
    const int l31  = lane & 31;
    const int lh   = lane >> 5;

    const int bp = blockIdx.x, bi = blockIdx.y;

    const u16* Ab = att + (long)bi * 128 * CDIM;
    const u16* Bb = qT  + (long)bp * 128 * CDIM;

    f32x16 acc[2][2];
    {
        f32x16 z;
#pragma unroll
        for (int r = 0; r < 16; ++r) z[r] = 0.f;
        acc[0][0] = z; acc[0][1] = z; acc[1][0] = z; acc[1][1] = z;
    }

    stage_tile(Ab, CDIM, 0, sA[0], tid);
    stage_tile(Bb, CDIM, 0, sB[0], tid);
    asm volatile("s_waitcnt vmcnt(0)" ::: "memory");
    __syncthreads();

    int buf = 0;
    for (int t = 0; t < 16; ++t) {
        if (t < 15) {
            stage_tile(Ab, CDIM, t + 1, sA[buf ^ 1], tid);
            stage_tile(Bb, CDIM, t + 1, sB[buf ^ 1], tid);
        }
#pragma unroll
        for (int kk = 0; kk < 4; ++kk) {
            const int s = (kk << 1) + lh;
            bf16x8 a0 = rd_frag(sA[buf], wm * 64 + l31,      s);
            bf16x8 a1 = rd_frag(sA[buf], wm * 64 + 32 + l31, s);
            bf16x8 b0 = rd_frag(sB[buf], wn * 64 + l31,      s);
            bf16x8 b1 = rd_frag(sB[buf], wn * 64 + 32 + l31, s);
            acc[0][0] = mfma32(a0, b0, acc[0][0]);
            acc[0][1] = mfma32(a0, b1, acc[0][1]);
            acc[1][0] = mfma32(a1, b0, acc[1][0]);
            acc[1][1] = mfma32(a1, b1, acc[1][1]);
        }
        asm volatile("s_waitcnt vmcnt(0)" ::: "memory");
        __syncthreads();
        buf ^= 1;
    }

    const float gm = gamma[0];
#pragma unroll
    for (int m = 0; m < 2; ++m)
#pragma unroll
        for (int n = 0; n < 2; ++n)
#pragma unroll
            for (int r = 0; r < 16; ++r) {
                const int row = bi * 128 + wm * 64 + m * 32 + (r & 3) + ((r >> 2) << 3) + (lh << 2);
                const int col = bp * 128 + wn * 64 + n * 32 + l31;
                const long idx = (long)row * HW + col;
                out[idx] = gm * acc[m][n][r] + x[idx];
            }
}

extern "C" void kernel_launch(void* const* d_in, const int* in_sizes, int n_in,
                              void* d_out, int out_size, void* d_ws, size_t ws_size,
                              hipStream_t stream)
{
    (void)in_sizes; (void)n_in; (void)out_size; (void)ws_size;
    const float* x = (const float*)d_in[0];
    const float* gamma = (const float*)d_in[1];
    float* out = (float*)d_out;
    char* ws = (char*)d_ws;

    // Workspace (102 MiB, proven to fit): hi | lo | hiT | Esym | att.
    // Split-K partials (2 x 16 MiB) live in d_out (64 MiB), fully overwritten by k_out.
    u16*   hi   = (u16*)ws;                         // 32 MiB
    u16*   lo   = (u16*)(ws + (32ull << 20));       // 32 MiB
    u16*   hiT  = (u16*)(ws + (64ull << 20));       // 32 MiB
    float* Esym = (float*)(ws + (96ull << 20));     //  4 MiB
    u16*   att  = (u16*)(ws + (100ull << 20));      //  2 MiB
    float* E1p  = out;                              // 16 MiB (4 splits x 4 MiB)
    float* E2p  = out + 4ull * CDIM * CDIM;         // 16 MiB

    k_convert<<<dim3(256, 16), 256, 0, stream>>>(x, hi, lo, hiT);
    // Energy: 8x8 tile grid x split-K 4 = 256 blocks (1/CU), kchunk = 4096.
    k_energy<<<dim3(8, 8, 4), 256, 0, stream>>>(hi, lo, E1p, E2p, 4096);
    k_symmetrize<<<dim3(16, 16), 256, 0, stream>>>(E1p, E2p, Esym);
    k_softmax<<<1024, 256, 0, stream>>>(Esym, att);
    // Out: GEMM M=1024, N=16384, K=1024; epilogue gamma*acc + x.  grid 128x8, 2 blocks/CU.
    k_out<<<dim3(128, 8), 256, 0, stream>>>(att, hiT, x, gamma, out);
}

// Round 9
// 210.954 us; speedup vs baseline: 1.2815x; 1.2815x over previous
//
#include <hip/hip_runtime.h>
#include <hip/hip_bf16.h>

typedef unsigned short u16;
typedef float    f32x16 __attribute__((ext_vector_type(16)));
typedef short    s16x8  __attribute__((ext_vector_type(8)));
typedef short    bf16x8 __attribute__((ext_vector_type(8)));
typedef _Float16 f16x8  __attribute__((ext_vector_type(8)));
typedef u16      u16x8  __attribute__((ext_vector_type(8)));

#define CDIM 1024
#define HW   16384

typedef const void __attribute__((address_space(1))) gvoid;
typedef void __attribute__((address_space(3))) svoid;

__device__ __forceinline__ u16 f2bf(float f) {
    unsigned u = __float_as_uint(f);
    u += 0x7fffu + ((u >> 16) & 1u);            // RNE
    return (u16)(u >> 16);
}
__device__ __forceinline__ float bf2f(u16 h) { return __uint_as_float(((unsigned)h) << 16); }
__device__ __forceinline__ u16 f2h(float f) {
    _Float16 h = (_Float16)f;                   // RNE
    u16 b; __builtin_memcpy(&b, &h, 2); return b;
}

__device__ __forceinline__ f32x16 mfma32(bf16x8 a, bf16x8 b, f32x16 c) {
    return __builtin_amdgcn_mfma_f32_32x32x16_bf16(a, b, c, 0, 0, 0);
}
__device__ __forceinline__ f32x16 mfma32h(f16x8 a, f16x8 b, f32x16 c) {
    return __builtin_amdgcn_mfma_f32_32x32x16_f16(a, b, c, 0, 0, 0);
}

// pair enumeration for the triangular energy grid: (bi,bj), 0 <= bi <= bj <= 7
__device__ __constant__ int PAIRI[36] = {0,0,0,0,0,0,0,0, 1,1,1,1,1,1,1, 2,2,2,2,2,2,
                                         3,3,3,3,3, 4,4,4,4, 5,5,5, 6,6, 7};
__device__ __constant__ int PAIRJ[36] = {0,1,2,3,4,5,6,7, 1,2,3,4,5,6,7, 2,3,4,5,6,7,
                                         3,4,5,6,7, 4,5,6,7, 5,6,7, 6,7, 7};

// ---------------- K1: x(f32) -> hi, lo (bf16 split) + fhT (fp16 transpose, for PV) ------
__global__ __launch_bounds__(256) void k_convert(const float* __restrict__ x,
                                                 u16* __restrict__ hi, u16* __restrict__ lo,
                                                 u16* __restrict__ fhT)
{
    __shared__ u16 tile[64][72];
    const int pb = blockIdx.x;   // HW tile (0..255)
    const int cb = blockIdx.y;   // C tile  (0..15)
    const int tid = threadIdx.x;
#pragma unroll
    for (int pass = 0; pass < 4; ++pass) {
        const int i  = (tid >> 4) + (pass << 4);    // c-row in tile 0..63
        const int j4 = (tid & 15) << 2;             // p-col in tile
        const long gidx = (long)(cb * 64 + i) * HW + pb * 64 + j4;
        const float4 v = *(const float4*)(x + gidx);
        ushort4 h, l;
        h.x = f2bf(v.x); l.x = f2bf(v.x - bf2f(h.x));
        h.y = f2bf(v.y); l.y = f2bf(v.y - bf2f(h.y));
        h.z = f2bf(v.z); l.z = f2bf(v.z - bf2f(h.z));
        h.w = f2bf(v.w); l.w = f2bf(v.w - bf2f(h.w));
        *(ushort4*)(hi + gidx) = h;
        *(ushort4*)(lo + gidx) = l;
        tile[i][j4 + 0] = f2h(v.x); tile[i][j4 + 1] = f2h(v.y);
        tile[i][j4 + 2] = f2h(v.z); tile[i][j4 + 3] = f2h(v.w);
    }
    __syncthreads();
#pragma unroll
    for (int pass = 0; pass < 2; ++pass) {
        const int j  = (tid >> 3) + (pass << 5);    // p-row 0..63
        const int c8 = (tid & 7) << 3;
        u16x8 v;
#pragma unroll
        for (int q = 0; q < 8; ++q) v[q] = tile[c8 + q][j];
        *(u16x8*)(fhT + (long)(pb * 64 + j) * CDIM + cb * 64 + c8) = v;
    }
}

// ---- LDS involution placement (R4-R7-proven staging/read pair), 256-thread version ----
// Granule (row, s) of a 128x64 16-bit tile lives at u16 offset (row>>3)*512 + s*64 + ((row&7)^s)*8.
__device__ __forceinline__ void stage_tile(const u16* __restrict__ gbase, long ldg,
                                           int ktile, u16* seg, int tid)
{
    const int lane = tid & 63;
    const int wv   = tid >> 6;                  // 0..3
    const int s    = lane >> 3;                 // k-slot 0..7 (16B granules)
    const int r7   = (lane & 7) ^ s;            // row within 8-row region
    const int col  = s << 3;                    // element col of the granule
#pragma unroll
    for (int q = 0; q < 4; ++q) {
        const int j = wv + (q << 2);            // region 0..15 (8 rows each)
        const u16* src = gbase + (long)((j << 3) + r7) * ldg + (ktile << 6) + col;
        __builtin_amdgcn_global_load_lds((gvoid*)src, (svoid*)(seg + (j << 9)), 16, 0, 0);
    }
}

__device__ __forceinline__ bf16x8 rd_frag(const u16* seg, int row, int s)
{
    const int off = ((row >> 3) << 9) + (s << 6) + (((row & 7) ^ s) << 3);
    return *(const bf16x8*)(seg + off);
}
__device__ __forceinline__ f16x8 rd_fragh(const u16* seg, int row, int s)
{
    const int off = ((row >> 3) << 9) + (s << 6) + (((row & 7) ^ s) << 3);
    s16x8 v = *(const s16x8*)(seg + off);
    return __builtin_bit_cast(f16x8, v);
}

// ---------------- K2: triangular-pair energy GEMM (bf16 split) ----------------
// Block = pair (bi<=bj) x split-K slice.  Computes the full-precision tile
//   Efull = H_bi.H_bj^T + H_bi.L_bj^T + L_bi.H_bj^T   (L.L^T dropped, ~1e-3)
// and writes it at (bi,bj) AND mirrored at (bj,bi)  ->  no symmetrize pass.
// Body: R1-champion structure (BK=64, dbuf, stage-early, vmcnt(0)+syncthreads),
// 4 staged tiles, 8 reads : 12 MFMA per kk.  128 KB LDS, 1 block/CU.
__global__ __launch_bounds__(256, 1) void k_energy(const u16* __restrict__ hi,
                                                   const u16* __restrict__ lo,
                                                   float* __restrict__ Ep)
{
    __shared__ u16 smem[2][4][8192];   // [buf][Ha,La,Hb,Lb]  = 128 KB

    const int tid  = threadIdx.x;
    const int lane = tid & 63;
    const int w    = tid >> 6;
    const int wm   = w >> 1;          // 0..1
    const int wn   = w & 1;           // 0..1
    const int l31  = lane & 31;
    const int lh   = lane >> 5;       // k-half

    const int pr = blockIdx.x;        // 0..35
    const int ks = blockIdx.y;        // 0..6
    const int bi = PAIRI[pr], bj = PAIRJ[pr];
    const int k0  = ks * 2368;        // 6 x 2368 + 2176 = 16384 (all multiples of 64)
    const int nkt = (ks == 6) ? 34 : 37;

    const u16* Ha = hi + (long)bi * 128 * HW + k0;
    const u16* La = lo + (long)bi * 128 * HW + k0;
    const u16* Hb = hi + (long)bj * 128 * HW + k0;
    const u16* Lb = lo + (long)bj * 128 * HW + k0;

    f32x16 acc1[2][2], acc2[2][2], acc3[2][2];
    {
        f32x16 z;
#pragma unroll
        for (int r = 0; r < 16; ++r) z[r] = 0.f;
#pragma unroll
        for (int m = 0; m < 2; ++m)
#pragma unroll
            for (int n = 0; n < 2; ++n) { acc1[m][n] = z; acc2[m][n] = z; acc3[m][n] = z; }
    }

    stage_tile(Ha, HW, 0, smem[0][0], tid);
    stage_tile(La, HW, 0, smem[0][1], tid);
    stage_tile(Hb, HW, 0, smem[0][2], tid);
    stage_tile(Lb, HW, 0, smem[0][3], tid);
    asm volatile("s_waitcnt vmcnt(0)" ::: "memory");
    __syncthreads();

    int buf = 0;
    for (int t = 0; t < nkt; ++t) {
        if (t + 1 < nkt) {
            stage_tile(Ha, HW, t + 1, smem[buf ^ 1][0], tid);
            stage_tile(La, HW, t + 1, smem[buf ^ 1][1], tid);
            stage_tile(Hb, HW, t + 1, smem[buf ^ 1][2], tid);
            stage_tile(Lb, HW, t + 1, smem[buf ^ 1][3], tid);
        }
#pragma unroll
        for (int kk = 0; kk < 4; ++kk) {
            const int s = (kk << 1) + lh;
            bf16x8 a0  = rd_frag(smem[buf][0], wm * 64 + l31,      s);
            bf16x8 a1  = rd_frag(smem[buf][0], wm * 64 + 32 + l31, s);
            bf16x8 la0 = rd_frag(smem[buf][1], wm * 64 + l31,      s);
            bf16x8 la1 = rd_frag(smem[buf][1], wm * 64 + 32 + l31, s);
            bf16x8 b0  = rd_frag(smem[buf][2], wn * 64 + l31,      s);
            bf16x8 b1  = rd_frag(smem[buf][2], wn * 64 + 32 + l31, s);
            bf16x8 lb0 = rd_frag(smem[buf][3], wn * 64 + l31,      s);
            bf16x8 lb1 = rd_frag(smem[buf][3], wn * 64 + 32 + l31, s);
            acc1[0][0] = mfma32(a0, b0, acc1[0][0]);
            acc1[0][1] = mfma32(a0, b1, acc1[0][1]);
            acc1[1][0] = mfma32(a1, b0, acc1[1][0]);
            acc1[1][1] = mfma32(a1, b1, acc1[1][1]);
            acc2[0][0] = mfma32(a0, lb0, acc2[0][0]);
            acc2[0][1] = mfma32(a0, lb1, acc2[0][1]);
            acc2[1][0] = mfma32(a1, lb0, acc2[1][0]);
            acc2[1][1] = mfma32(a1, lb1, acc2[1][1]);
            acc3[0][0] = mfma32(la0, b0, acc3[0][0]);
            acc3[0][1] = mfma32(la0, b1, acc3[0][1]);
            acc3[1][0] = mfma32(la1, b0, acc3[1][0]);
            acc3[1][1] = mfma32(la1, b1, acc3[1][1]);
        }
        asm volatile("s_waitcnt vmcnt(0)" ::: "memory");
        __syncthreads();
        buf ^= 1;
    }

    // epilogue: 32x32 C/D layout (verified): col = lane&31, row = (r&3) + 8*(r>>2) + 4*(lane>>5)
    float* e = Ep + (long)ks * (CDIM * CDIM);
#pragma unroll
    for (int m = 0; m < 2; ++m)
#pragma unroll
        for (int n = 0; n < 2; ++n) {
            f32x16 sm;
#pragma unroll
            for (int r = 0; r < 16; ++r) sm[r] = acc1[m][n][r] + acc2[m][n][r] + acc3[m][n][r];
            // straight write at (bi,bj)
#pragma unroll
            for (int r = 0; r < 16; ++r) {
                const int row = bi * 128 + wm * 64 + m * 32 + (r & 3) + ((r >> 2) << 3) + (lh << 2);
                const int col = bj * 128 + wn * 64 + n * 32 + l31;
                e[(long)row * CDIM + col] = sm[r];
            }
            // mirror write at (bj,bi): lane holds 4 consecutive cols per reg-quad
            if (bi != bj) {
                const int mrow = bj * 128 + wn * 64 + n * 32 + l31;
#pragma unroll
                for (int rq = 0; rq < 4; ++rq) {
                    const int mcol = bi * 128 + wm * 64 + m * 32 + (rq << 3) + (lh << 2);
                    float4 v4 = make_float4(sm[rq * 4 + 0], sm[rq * 4 + 1],
                                            sm[rq * 4 + 2], sm[rq * 4 + 3]);
                    *(float4*)(e + (long)mrow * CDIM + mcol) = v4;
                }
            }
        }
}

// ---------------- K3: att = softmax(-E) rows; folds the 7 split-K partials; fp16 out ----
__global__ __launch_bounds__(256) void k_softmax(const float* __restrict__ Ep,
                                                 u16* __restrict__ att)
{
    __shared__ float red[4];
    __shared__ float bcast;
    const int row = blockIdx.x, tid = threadIdx.x;

    float4 v = make_float4(0.f, 0.f, 0.f, 0.f);
#pragma unroll
    for (int ks = 0; ks < 7; ++ks) {
        const float4 p = ((const float4*)(Ep + (long)ks * (CDIM * CDIM) + (long)row * CDIM))[tid];
        v.x += p.x; v.y += p.y; v.z += p.z; v.w += p.w;
    }

    float m = fminf(fminf(v.x, v.y), fminf(v.z, v.w));
#pragma unroll
    for (int s = 32; s > 0; s >>= 1) m = fminf(m, __shfl_down(m, s));
    if ((tid & 63) == 0) red[tid >> 6] = m;
    __syncthreads();
    if (tid == 0) bcast = fminf(fminf(red[0], red[1]), fminf(red[2], red[3]));
    __syncthreads();
    m = bcast;  // row min of E == row max of -E

    const float px = expf(m - v.x), py = expf(m - v.y), pz = expf(m - v.z), pw = expf(m - v.w);
    float s4 = px + py + pz + pw;
#pragma unroll
    for (int s = 32; s > 0; s >>= 1) s4 += __shfl_down(s4, s);
    if ((tid & 63) == 0) red[tid >> 6] = s4;
    __syncthreads();
    if (tid == 0) bcast = red[0] + red[1] + red[2] + red[3];
    __syncthreads();
    const float inv = 1.0f / bcast;

    ushort4 o;
    o.x = f2h(px * inv); o.y = f2h(py * inv); o.z = f2h(pz * inv); o.w = f2h(pw * inv);
    ((ushort4*)(att + (long)row * CDIM))[tid] = o;
}

// ---------------- K4: out = gamma * (att @ q) + x  (fp16 operands, R1-exact structure) ----
__global__ __launch_bounds__(256) void k_out(const u16* __restrict__ att, const u16* __restrict__ qT,
                                             const float* __restrict__ x, const float* __restrict__ gamma,
                                             float* __restrict__ out)
{
    __shared__ u16 sA[2][8192];
    __shared__ u16 sB[2][8192];

    const int tid  = threadIdx.x;
    const int lane = tid & 63;
    const int w    = tid >> 6;
    const int wm   = w >> 1;          // 0..1
    const int wn   = w & 1;           // 0..1
    const int l31  = lane & 31;
    const int lh   = lane >> 5;

    const int bp = blockIdx.x, bi = blockIdx.y;

    const u16* Ab = att + (long)bi * 128 * CDIM;
    const u16* Bb = qT  + (long)bp * 128 * CDIM;

    f32x16 acc[2][2];
    {
        f32x16 z;
#pragma unroll
        for (int r = 0; r < 16; ++r) z[r] = 0.f;
        acc[0][0] = z; acc[0][1] = z; acc[1][0] = z; acc[1][1] = z;
    }

    stage_tile(Ab, CDIM, 0, sA[0], tid);
    stage_tile(Bb, CDIM, 0, sB[0], tid);
    asm volatile("s_waitcnt vmcnt(0)" ::: "memory");
    __syncthreads();

    int buf = 0;
    for (int t = 0; t < 16; ++t) {
        if (t < 15) {
            stage_tile(Ab, CDIM, t + 1, sA[buf ^ 1], tid);
            stage_tile(Bb, CDIM, t + 1, sB[buf ^ 1], tid);
        }
#pragma unroll
        for (int kk = 0; kk < 4; ++kk) {
            const int s = (kk << 1) + lh;
            f16x8 a0 = rd_fragh(sA[buf], wm * 64 + l31,      s);
            f16x8 a1 = rd_fragh(sA[buf], wm * 64 + 32 + l31, s);
            f16x8 b0 = rd_fragh(sB[buf], wn * 64 + l31,      s);
            f16x8 b1 = rd_fragh(sB[buf], wn * 64 + 32 + l31, s);
            acc[0][0] = mfma32h(a0, b0, acc[0][0]);
            acc[0][1] = mfma32h(a0, b1, acc[0][1]);
            acc[1][0] = mfma32h(a1, b0, acc[1][0]);
            acc[1][1] = mfma32h(a1, b1, acc[1][1]);
        }
        asm volatile("s_waitcnt vmcnt(0)" ::: "memory");
        __syncthreads();
        buf ^= 1;
    }

    const float gm = gamma[0];
#pragma unroll
    for (int m = 0; m < 2; ++m)
#pragma unroll
        for (int n = 0; n < 2; ++n)
#pragma unroll
            for (int r = 0; r < 16; ++r) {
                const int row = bi * 128 + wm * 64 + m * 32 + (r & 3) + ((r >> 2) << 3) + (lh << 2);
                const int col = bp * 128 + wn * 64 + n * 32 + l31;
                const long idx = (long)row * HW + col;
                out[idx] = gm * acc[m][n][r] + x[idx];
            }
}

extern "C" void kernel_launch(void* const* d_in, const int* in_sizes, int n_in,
                              void* d_out, int out_size, void* d_ws, size_t ws_size,
                              hipStream_t stream)
{
    (void)in_sizes; (void)n_in; (void)out_size; (void)ws_size;
    const float* x = (const float*)d_in[0];
    const float* gamma = (const float*)d_in[1];
    float* out = (float*)d_out;
    char* ws = (char*)d_ws;

    // Workspace (98 MiB of the proven-fitting 102 MiB): hi | lo | fhT | att.
    // Split-K energy partials (7 x 4 MiB = 28 MiB) live in d_out (64 MiB), fully
    // overwritten by k_out afterwards.
    u16*   hi  = (u16*)ws;                          // 32 MiB (bf16 hi)
    u16*   lo  = (u16*)(ws + (32ull << 20));        // 32 MiB (bf16 lo)
    u16*   fhT = (u16*)(ws + (64ull << 20));        // 32 MiB (fp16 x^T for PV)
    u16*   att = (u16*)(ws + (96ull << 20));        //  2 MiB (fp16 attention)
    float* Ep  = out;                               // 28 MiB scratch in d_out

    k_convert<<<dim3(256, 16), 256, 0, stream>>>(x, hi, lo, fhT);
    // Energy: triangular pairs (36) x split-K (7) = 252 blocks; each writes tile + mirror.
    k_energy<<<dim3(36, 7), 256, 0, stream>>>(hi, lo, Ep);
    // Softmax folds the 7 split-K partials; no symmetrize pass needed.
    k_softmax<<<1024, 256, 0, stream>>>(Ep, att);
    // Out: GEMM M=1024, N=16384, K=1024 (fp16); epilogue gamma*acc + x.
    k_out<<<dim3(128, 8), 256, 0, stream>>>(att, fhT, x, gamma, out);
}